// Round 10
// baseline (422.693 us; speedup 1.0000x reference)
//
#include <hip/hip_runtime.h>
#include <hip/hip_bf16.h>
#include <hip/hip_cooperative_groups.h>
#include <stdint.h>

namespace cg = cooperative_groups;

#define G_ 8
#define T_ 1024
#define K_ 7168
#define N_ 2048
#define KB_ 56         // K/128 quant blocks
#define NB_ 16         // N/128
#define NT8_ 56        // K-tiles of 128

#define ACT_WGS  57344   // (G*T*KB)/8
#define WREC_WGS 28672   // (G*N*K/16)/256
#define COOP_WGS 512     // 2 blocks/CU x 256 CUs

typedef __attribute__((ext_vector_type(4))) float f32x4;
typedef __attribute__((ext_vector_type(8))) int   i32x8;

typedef __attribute__((address_space(3))) uint32_t lds_u32_t;
typedef const __attribute__((address_space(1))) uint32_t gbl_u32_t;

__device__ __forceinline__ void gload_lds16(const void* gsrc, const void* ldst)
{
    __builtin_amdgcn_global_load_lds(
        (gbl_u32_t*)(uintptr_t)gsrc,
        (lds_u32_t*)(uint32_t)(uintptr_t)ldst, 16, 0, 0);
}

__device__ __forceinline__ void blockbar()
{
    asm volatile("" ::: "memory");
    __builtin_amdgcn_s_barrier();
    asm volatile("" ::: "memory");
}

// ---------------------------------------------------------------------------
// prep bodies (verified rounds 6-9)
// ---------------------------------------------------------------------------
__device__ __forceinline__ void act_body(
    int abid, int tid, const float* __restrict__ xs,
    uint8_t* __restrict__ xq8, float* __restrict__ ascale)
{
    const int grp = (abid * 256 + tid) >> 5;
    const int l   = tid & 31;
    const size_t base = (size_t)grp * 128 + (size_t)l * 4;

    const float4 v = *(const float4*)(xs + base);
    float am = fmaxf(fmaxf(fabsf(v.x), fabsf(v.y)),
                     fmaxf(fabsf(v.z), fabsf(v.w)));
#pragma unroll
    for (int off = 1; off <= 16; off <<= 1)
        am = fmaxf(am, __shfl_xor(am, off, 64));

    const float rs = 448.0f / am;
    const float s  = am * (1.0f / 448.0f);

    int pk = __builtin_amdgcn_cvt_pk_fp8_f32(v.x * rs, v.y * rs, 0, false);
    pk     = __builtin_amdgcn_cvt_pk_fp8_f32(v.z * rs, v.w * rs, pk, true);
    *(uint32_t*)(xq8 + base) = (uint32_t)pk;

    if (l == 0) {
        const int kb = grp % KB_;
        const int t  = (grp / KB_) & (T_ - 1);
        const int g  = grp / (KB_ * T_);
        ascale[(((size_t)(g * 4 + (t >> 8))) * KB_ + kb) * 256 + (t & 255)] = s;
    }
}

__device__ __forceinline__ void wrec_body(
    int wbid, int tid, const float* __restrict__ w, uint8_t* __restrict__ wq8)
{
    const size_t i = ((size_t)wbid * 256 + tid) * 16;
    uint32_t o[4];
#pragma unroll
    for (int q = 0; q < 4; ++q) {
        const float4 a = *(const float4*)(w + i + q * 4);
        int pk = __builtin_amdgcn_cvt_pk_fp8_f32(a.x, a.y, 0, false);
        pk     = __builtin_amdgcn_cvt_pk_fp8_f32(a.z, a.w, pk, true);
        o[q] = (uint32_t)pk;
    }
    *(uint4*)(wq8 + i) = make_uint4(o[0], o[1], o[2], o[3]);
}

// ---------------------------------------------------------------------------
// gemm tile body: 128x128, BK=128, 4 waves, round-8 schedule (one barrier +
// one vmcnt(0) per K-tile), XOR-swizzled DMA staging, mfma_scale 16x16x128,
// ascale/wsc hoisted out of the MFMA cluster, f32x4 rescale.
// LDS: A 2x16K @0 | B 2x16K @32768 | ascale 2x4K @65536 | wscale @73728.
// ---------------------------------------------------------------------------
union Frag { i32x8 v; struct { int4 lo, hi; } p; };

#define RD_FRAG(dst, base, r)                                                 \
  { const int rx_ = ((r) & 7) << 4;                                           \
    const char* bp_ = smem + (base) + (r)*128;                                \
    dst.p.lo = *(const int4*)(bp_ + ((lhi*32) ^ rx_));                        \
    dst.p.hi = *(const int4*)(bp_ + ((lhi*32 + 16) ^ rx_)); }

#define STG_A(c, t, bb) gload_lds16(pA8[c] + (size_t)(t)*128,                 \
      smem + (bb)*16384 + (c)*4096 + tid*16)
#define STG_B(c, t, bb) gload_lds16(pB8[c] + (size_t)(t)*128,                 \
      smem + 32768 + (bb)*16384 + (c)*4096 + tid*16)
#define STG_S(c) gload_lds16(pS + (size_t)(c)*2048,                           \
      smem + 65536 + ((c)&1)*4096 + tid*16)

__device__ __forceinline__ void gemm_tile(
    char* smem, int g, int inner, int tid,
    const uint8_t* __restrict__ xq8, const uint8_t* __restrict__ wq8,
    const float* __restrict__ ascale, const float* __restrict__ wscale,
    const float* __restrict__ bias, float* __restrict__ y)
{
    const int tn = inner & 15;
    const int tm = inner >> 4;
    const int t0 = tm * 128, n0 = tn * 128;

    const int lane = tid & 63, wid = tid >> 6;
    const int l15 = lane & 15, lhi = lane >> 4;
    const int wrow = (wid >> 1) * 64;
    const int wcol = (wid & 1) * 64;

    const uint8_t* Ag = xq8 + (size_t)g * T_ * K_;
    const uint8_t* Bg = wq8 + (size_t)g * N_ * K_;

    const int srow = tid >> 3;
    const int xoff = ((tid & 7) ^ (srow & 7)) * 16;
    const uint8_t* pA8[4];
    const uint8_t* pB8[4];
#pragma unroll
    for (int c = 0; c < 4; ++c) {
        pA8[c] = Ag + (size_t)(t0 + c * 32 + srow) * K_ + xoff;
        pB8[c] = Bg + (size_t)(n0 + c * 32 + srow) * K_ + xoff;
    }

    const float* pS = ascale + ((size_t)(g * 4 + (tm >> 1)) * KB_) * 256
                    + (tid >> 5) * 256 + (tm & 1) * 128 + (tid & 31) * 4;

    const f32x4 z4 = {0.f, 0.f, 0.f, 0.f};
    f32x4 acc[4][4] = {};
    Frag bF[4];
    f32x4 asv[4];

    // ---- safety barrier (t-loop reuse of LDS), then prologue ----
    blockbar();
    if (tid < KB_) {
        const float wv = wscale[((size_t)(g * NB_ + tn)) * KB_ + tid];
        *(float*)(smem + 73728 + tid * 4) = wv;
    }
    STG_S(0);
#pragma unroll
    for (int c = 0; c < 4; ++c) { STG_A(c, 0, 0); STG_B(c, 0, 0); }
    asm volatile("s_waitcnt vmcnt(0)" ::: "memory");
    asm volatile("s_waitcnt lgkmcnt(0)" ::: "memory");
    blockbar();

    for (int u = 0; u < NT8_; ++u) {
        const int cur = u & 1, nxt = cur ^ 1;
        const bool pf = (u + 1 < NT8_);
        const int sbuf = (u >> 3) & 1;

        // ---- stage issue first: [ascale chunk]; A+B tile u+1 ----
        if ((u & 7) == 0 && u + 8 < NT8_) STG_S((u >> 3) + 1);
        if (pf) {
#pragma unroll
            for (int c = 0; c < 4; ++c) { STG_A(c, u + 1, nxt); STG_B(c, u + 1, nxt); }
        }

        const float wsc = *(const float*)(smem + 73728 + u * 4);

        // ---- hoist: B frags + all rescale factors (LDS) out of MFMA body ----
#pragma unroll
        for (int n = 0; n < 4; ++n)
            RD_FRAG(bF[n], 32768 + cur * 16384, wcol + n * 16 + l15);
#pragma unroll
        for (int m = 0; m < 4; ++m) {
            const float4 sv = *(const float4*)(smem + 65536 + sbuf * 4096 +
                (u & 7) * 512 + (wrow + m * 16 + lhi * 4) * 4);
            asv[m][0] = sv.x * wsc; asv[m][1] = sv.y * wsc;
            asv[m][2] = sv.z * wsc; asv[m][3] = sv.w * wsc;
        }

        // ---- pure MFMA + pk-fma cluster ----
        __builtin_amdgcn_s_setprio(1);
#pragma unroll
        for (int m = 0; m < 4; ++m) {
            Frag aF;
            RD_FRAG(aF, cur * 16384, wrow + m * 16 + l15);
#pragma unroll
            for (int n = 0; n < 4; ++n) {
                f32x4 blk = __builtin_amdgcn_mfma_scale_f32_16x16x128_f8f6f4(
                    aF.v, bF[n].v, z4, 0, 0, 0, 0x7F7F7F7F, 0, 0x7F7F7F7F);
                acc[m][n] += blk * asv[m];
            }
        }
        __builtin_amdgcn_s_setprio(0);

        // ---- single drain + barrier per K-tile ----
        if (pf) {
            asm volatile("s_waitcnt vmcnt(0)" ::: "memory");
            blockbar();
        }
    }

    // ---- epilogue ----
    float* Yg = y + (size_t)g * T_ * N_;
#pragma unroll
    for (int n = 0; n < 4; ++n) {
        const int col = n0 + wcol + n * 16 + l15;
        const float bv = bias[g * N_ + col];
#pragma unroll
        for (int m = 0; m < 4; ++m) {
            const int r0 = t0 + wrow + m * 16 + lhi * 4;
#pragma unroll
            for (int j = 0; j < 4; ++j)
                Yg[(size_t)(r0 + j) * N_ + col] = acc[m][n][j] + bv;
        }
    }
}

// ---------------------------------------------------------------------------
// Cooperative fused kernel: grid-strided prep -> grid.sync -> 2 gemm tiles.
// 512 blocks x 256 threads, 74 KB LDS -> 2 blocks/CU, all co-resident.
// ---------------------------------------------------------------------------
__global__ __launch_bounds__(256, 2) void fused_kernel(
    const float* __restrict__ xs, const float* __restrict__ w,
    const float* __restrict__ wscale, const float* __restrict__ bias,
    uint8_t* __restrict__ xq8, float* __restrict__ ascale,
    uint8_t* __restrict__ wq8, float* __restrict__ y)
{
    __shared__ char smem[73952];
    const int b = blockIdx.x, tid = threadIdx.x;

    // phase 1: prep (grid-stride over the verified bodies)
    for (int abid = b; abid < ACT_WGS; abid += COOP_WGS)
        act_body(abid, tid, xs, xq8, ascale);
    for (int wbid = b; wbid < WREC_WGS; wbid += COOP_WGS)
        wrec_body(wbid, tid, w, wq8);

    cg::this_grid().sync();

    // phase 2: two gemm tiles; g = b&7 keeps the group->XCD mapping
    const int g = b & 7;
#pragma unroll 1
    for (int t = 0; t < 2; ++t) {
        const int inner = (b >> 3) * 2 + t;   // 0..127
        gemm_tile(smem, g, inner, tid, xq8, wq8, ascale, wscale, bias, y);
    }
}

// ---------------------------------------------------------------------------
// Fallback pair (round-8 verified path)
// ---------------------------------------------------------------------------
__global__ __launch_bounds__(256) void prep_kernel(
    const float* __restrict__ xs, uint8_t* __restrict__ xq8,
    float* __restrict__ ascale,
    const float* __restrict__ w, uint8_t* __restrict__ wq8)
{
    const int bid = blockIdx.x;
    if (bid < ACT_WGS) act_body(bid, threadIdx.x, xs, xq8, ascale);
    else               wrec_body(bid - ACT_WGS, threadIdx.x, w, wq8);
}

__global__ __launch_bounds__(256, 2) void gemm_fp8_kernel(
    const uint8_t* __restrict__ xq8, const uint8_t* __restrict__ wq8,
    const float* __restrict__ ascale, const float* __restrict__ wscale,
    const float* __restrict__ bias, float* __restrict__ y)
{
    __shared__ char smem[73952];
    const int bx0 = blockIdx.x;
    gemm_tile(smem, bx0 & 7, bx0 >> 3, threadIdx.x,
              xq8, wq8, ascale, wscale, bias, y);
}

// ---------------------------------------------------------------------------
extern "C" void kernel_launch(void* const* d_in, const int* in_sizes, int n_in,
                              void* d_out, int out_size, void* d_ws, size_t ws_size,
                              hipStream_t stream)
{
    const float* xs     = (const float*)d_in[0];
    const float* weight = (const float*)d_in[1];
    const float* scale  = (const float*)d_in[2];
    const float* bias   = (const float*)d_in[3];
    float* y = (float*)d_out;

    uint8_t* xq8  = (uint8_t*)d_ws;                      //  58,720,256 B
    float*   ascl = (float*)((char*)d_ws + 58720256);    //   1,835,008 B
    uint8_t* wq8  = (uint8_t*)((char*)d_ws + 60555264);  // 117,440,512 B

    int dev = 0, coop = 0;
    hipGetDevice(&dev);
    hipDeviceGetAttribute(&coop, hipDeviceAttributeCooperativeLaunch, dev);

    bool done = false;
    if (coop) {
        const float* a0 = xs;  const float* a1 = weight;
        const float* a2 = scale; const float* a3 = bias;
        uint8_t* a4 = xq8; float* a5 = ascl; uint8_t* a6 = wq8; float* a7 = y;
        void* kargs[] = { &a0, &a1, &a2, &a3, &a4, &a5, &a6, &a7 };
        hipError_t e = hipLaunchCooperativeKernel(
            (const void*)fused_kernel, dim3(COOP_WGS), dim3(256),
            kargs, 0, stream);
        done = (e == hipSuccess);
    }
    if (!done) {
        prep_kernel<<<ACT_WGS + WREC_WGS, 256, 0, stream>>>(
            xs, xq8, ascl, weight, wq8);
        gemm_fp8_kernel<<<G_ * (T_ / 128) * (N_ / 128), 256, 0, stream>>>(
            xq8, wq8, ascl, scale, bias, y);
    }
}

// Round 11
// 349.206 us; speedup vs baseline: 1.2104x; 1.2104x over previous
//
#include <hip/hip_runtime.h>
#include <hip/hip_bf16.h>
#include <stdint.h>

#define G_ 8
#define T_ 1024
#define K_ 7168
#define N_ 2048
#define KB_ 56         // K/128 quant blocks
#define NB_ 16         // N/128
#define NT8_ 56        // K-tiles of 128

#define ACT_WGS  57344   // (G*T*KB)/8
#define WREC_WGS 28672   // (G*N*K/16)/256

typedef __attribute__((ext_vector_type(4))) float f32x4;
typedef __attribute__((ext_vector_type(8))) int   i32x8;

typedef __attribute__((address_space(3))) uint32_t lds_u32_t;
typedef const __attribute__((address_space(1))) uint32_t gbl_u32_t;

__device__ __forceinline__ void gload_lds16(const void* gsrc, const void* ldst)
{
    __builtin_amdgcn_global_load_lds(
        (gbl_u32_t*)(uintptr_t)gsrc,
        (lds_u32_t*)(uint32_t)(uintptr_t)ldst, 16, 0, 0);
}

__device__ __forceinline__ void blockbar()
{
    asm volatile("" ::: "memory");
    __builtin_amdgcn_s_barrier();
    asm volatile("" ::: "memory");
}

// ---------------------------------------------------------------------------
// Kernel 1: fused prepass (verified rounds 6-9; high-occupancy launch).
//   Blocks [0, ACT_WGS): act quant -> fp8 bytes + scale table
//     scale layout [g][t>>8][kb][t&255]
//   Blocks [ACT_WGS, ..): weight recode fp32-held-codes -> fp8 bytes
// ---------------------------------------------------------------------------
__global__ __launch_bounds__(256) void prep_kernel(
    const float* __restrict__ xs, uint8_t* __restrict__ xq8,
    float* __restrict__ ascale,
    const float* __restrict__ w, uint8_t* __restrict__ wq8)
{
    const int bid = blockIdx.x;
    const int tid = threadIdx.x;
    if (bid < ACT_WGS) {
        const int grp = (bid * 256 + tid) >> 5;
        const int l   = tid & 31;
        const size_t base = (size_t)grp * 128 + (size_t)l * 4;

        const float4 v = *(const float4*)(xs + base);
        float am = fmaxf(fmaxf(fabsf(v.x), fabsf(v.y)),
                         fmaxf(fabsf(v.z), fabsf(v.w)));
#pragma unroll
        for (int off = 1; off <= 16; off <<= 1)
            am = fmaxf(am, __shfl_xor(am, off, 64));

        const float rs = 448.0f / am;
        const float s  = am * (1.0f / 448.0f);

        int pk = __builtin_amdgcn_cvt_pk_fp8_f32(v.x * rs, v.y * rs, 0, false);
        pk     = __builtin_amdgcn_cvt_pk_fp8_f32(v.z * rs, v.w * rs, pk, true);
        *(uint32_t*)(xq8 + base) = (uint32_t)pk;

        if (l == 0) {
            const int kb = grp % KB_;
            const int t  = (grp / KB_) & (T_ - 1);
            const int g  = grp / (KB_ * T_);
            ascale[(((size_t)(g * 4 + (t >> 8))) * KB_ + kb) * 256 + (t & 255)] = s;
        }
    } else {
        const size_t i = ((size_t)(bid - ACT_WGS) * 256 + tid) * 16;
        uint32_t o[4];
#pragma unroll
        for (int q = 0; q < 4; ++q) {
            const float4 a = *(const float4*)(w + i + q * 4);
            int pk = __builtin_amdgcn_cvt_pk_fp8_f32(a.x, a.y, 0, false);
            pk     = __builtin_amdgcn_cvt_pk_fp8_f32(a.z, a.w, pk, true);
            o[q] = (uint32_t)pk;
        }
        *(uint4*)(wq8 + i) = make_uint4(o[0], o[1], o[2], o[3]);
    }
}

// ---------------------------------------------------------------------------
// Kernel 2: blockwise-fp8 grouped GEMM, 128x128 tile, BK=128, 4 waves,
//   2 blocks/CU, ONE barrier + one vmcnt(0) per K-tile (round-8 schedule).
//   A+B fp8 via global_load_lds with XOR-swizzled sources.
//   NEW vs r8: ALL frag reads (4 aF + 4 bF = 16 ds_read_b128) and all
//   rescale factors hoisted ABOVE the MFMA cluster -> cluster is a pure
//   16 MFMA + 64 fmac run with no memory ops (no lgkm stalls inside).
//   LDS: A 2x16K @0 | B 2x16K @32768 | ascale 2x4K @65536 | wscale @73728.
// ---------------------------------------------------------------------------
union Frag { i32x8 v; struct { int4 lo, hi; } p; };

#define RD_FRAG(dst, base, r)                                                 \
  { const int rx_ = ((r) & 7) << 4;                                           \
    const char* bp_ = smem + (base) + (r)*128;                                \
    dst.p.lo = *(const int4*)(bp_ + ((lhi*32) ^ rx_));                        \
    dst.p.hi = *(const int4*)(bp_ + ((lhi*32 + 16) ^ rx_)); }

#define STG_A(c, t, bb) gload_lds16(pA8[c] + (size_t)(t)*128,                 \
      smem + (bb)*16384 + (c)*4096 + tid*16)
#define STG_B(c, t, bb) gload_lds16(pB8[c] + (size_t)(t)*128,                 \
      smem + 32768 + (bb)*16384 + (c)*4096 + tid*16)
#define STG_S(c) gload_lds16(pS + (size_t)(c)*2048,                           \
      smem + 65536 + ((c)&1)*4096 + tid*16)

__global__ __launch_bounds__(256, 2) void gemm_fp8_kernel(
    const uint8_t* __restrict__ xq8, const uint8_t* __restrict__ wq8,
    const float* __restrict__ ascale, const float* __restrict__ wscale,
    const float* __restrict__ bias, float* __restrict__ y)
{
    __shared__ char smem[73952];

    const int bx0 = blockIdx.x;
    const int g     = bx0 & 7;          // group == XCD (L2 slab sharing)
    const int inner = bx0 >> 3;         // 0..127
    const int tn    = inner & 15;       // 0..15
    const int tm    = inner >> 4;       // 0..7
    const int t0 = tm * 128, n0 = tn * 128;

    const int tid = threadIdx.x, lane = tid & 63, wid = tid >> 6;
    const int l15 = lane & 15, lhi = lane >> 4;
    const int wrow = (wid >> 1) * 64;
    const int wcol = (wid & 1) * 64;

    const uint8_t* Ag = xq8 + (size_t)g * T_ * K_;
    const uint8_t* Bg = wq8 + (size_t)g * N_ * K_;

    // staging maps: LDS(row = c*32 + tid/8, slot = tid&7) <- global slot^row&7
    const int srow = tid >> 3;
    const int xoff = ((tid & 7) ^ (srow & 7)) * 16;
    const uint8_t* pA8[4];
    const uint8_t* pB8[4];
#pragma unroll
    for (int c = 0; c < 4; ++c) {
        pA8[c] = Ag + (size_t)(t0 + c * 32 + srow) * K_ + xoff;
        pB8[c] = Bg + (size_t)(n0 + c * 32 + srow) * K_ + xoff;
    }

    // ascale chunk source: 8 kb x 128 tokens = 4KB per chunk
    const float* pS = ascale + ((size_t)(g * 4 + (tm >> 1)) * KB_) * 256
                    + (tid >> 5) * 256 + (tm & 1) * 128 + (tid & 31) * 4;

    const f32x4 z4 = {0.f, 0.f, 0.f, 0.f};
    f32x4 acc[4][4] = {};
    Frag aF[4], bF[4];
    f32x4 asv[4];

    // ---- prologue: wscale row, ascale chunk 0, tile 0 -> buf0 ----
    if (tid < KB_) {
        const float wv = wscale[((size_t)(g * NB_ + tn)) * KB_ + tid];
        *(float*)(smem + 73728 + tid * 4) = wv;
    }
    STG_S(0);
#pragma unroll
    for (int c = 0; c < 4; ++c) { STG_A(c, 0, 0); STG_B(c, 0, 0); }
    asm volatile("s_waitcnt vmcnt(0)" ::: "memory");
    asm volatile("s_waitcnt lgkmcnt(0)" ::: "memory");
    blockbar();

    for (int u = 0; u < NT8_; ++u) {
        const int cur = u & 1, nxt = cur ^ 1;
        const bool pf = (u + 1 < NT8_);
        const int sbuf = (u >> 3) & 1;

        // ---- stage issue first: [ascale chunk]; A+B tile u+1 ----
        if ((u & 7) == 0 && u + 8 < NT8_) STG_S((u >> 3) + 1);
        if (pf) {
#pragma unroll
            for (int c = 0; c < 4; ++c) { STG_A(c, u + 1, nxt); STG_B(c, u + 1, nxt); }
        }

        const float wsc = *(const float*)(smem + 73728 + u * 4);

        // ---- hoist ALL frag reads + rescale factors above the cluster ----
#pragma unroll
        for (int n = 0; n < 4; ++n)
            RD_FRAG(bF[n], 32768 + cur * 16384, wcol + n * 16 + l15);
#pragma unroll
        for (int m = 0; m < 4; ++m)
            RD_FRAG(aF[m], cur * 16384, wrow + m * 16 + l15);
#pragma unroll
        for (int m = 0; m < 4; ++m) {
            const float4 sv = *(const float4*)(smem + 65536 + sbuf * 4096 +
                (u & 7) * 512 + (wrow + m * 16 + lhi * 4) * 4);
            asv[m][0] = sv.x * wsc; asv[m][1] = sv.y * wsc;
            asv[m][2] = sv.z * wsc; asv[m][3] = sv.w * wsc;
        }

        // ---- pure MFMA + pk-fma cluster (no memory ops inside) ----
        __builtin_amdgcn_s_setprio(1);
#pragma unroll
        for (int m = 0; m < 4; ++m) {
#pragma unroll
            for (int n = 0; n < 4; ++n) {
                f32x4 blk = __builtin_amdgcn_mfma_scale_f32_16x16x128_f8f6f4(
                    aF[m].v, bF[n].v, z4, 0, 0, 0, 0x7F7F7F7F, 0, 0x7F7F7F7F);
                acc[m][n] += blk * asv[m];
            }
        }
        __builtin_amdgcn_s_setprio(0);

        // ---- single drain + barrier per K-tile ----
        if (pf) {
            asm volatile("s_waitcnt vmcnt(0)" ::: "memory");
            blockbar();
        }
    }

    // ---- epilogue: C/D layout col = lane&15, row = (lane>>4)*4 + j ----
    float* Yg = y + (size_t)g * T_ * N_;
#pragma unroll
    for (int n = 0; n < 4; ++n) {
        const int col = n0 + wcol + n * 16 + l15;
        const float bv = bias[g * N_ + col];
#pragma unroll
        for (int m = 0; m < 4; ++m) {
            const int r0 = t0 + wrow + m * 16 + lhi * 4;
#pragma unroll
            for (int j = 0; j < 4; ++j)
                Yg[(size_t)(r0 + j) * N_ + col] = acc[m][n][j] + bv;
        }
    }
}

// ---------------------------------------------------------------------------
extern "C" void kernel_launch(void* const* d_in, const int* in_sizes, int n_in,
                              void* d_out, int out_size, void* d_ws, size_t ws_size,
                              hipStream_t stream)
{
    const float* xs     = (const float*)d_in[0];
    const float* weight = (const float*)d_in[1];
    const float* scale  = (const float*)d_in[2];
    const float* bias   = (const float*)d_in[3];
    float* y = (float*)d_out;

    uint8_t* xq8  = (uint8_t*)d_ws;                      //  58,720,256 B
    float*   ascl = (float*)((char*)d_ws + 58720256);    //   1,835,008 B
    uint8_t* wq8  = (uint8_t*)((char*)d_ws + 60555264);  // 117,440,512 B

    prep_kernel<<<ACT_WGS + WREC_WGS, 256, 0, stream>>>(
        xs, xq8, ascl, weight, wq8);

    gemm_fp8_kernel<<<G_ * (T_ / 128) * (N_ / 128), 256, 0, stream>>>(
        xq8, wq8, ascl, scale, bias, y);
}

// Round 12
// 326.337 us; speedup vs baseline: 1.2953x; 1.0701x over previous
//
#include <hip/hip_runtime.h>
#include <hip/hip_bf16.h>
#include <stdint.h>

#define G_ 8
#define T_ 1024
#define K_ 7168
#define N_ 2048
#define KB_ 56         // K/128 quant blocks
#define NB_ 16         // N/128
#define NT8_ 56        // K-tiles of 128

#define ACT_WGS  57344   // (G*T*KB)/8
#define WREC_WGS 28672   // (G*N*K/16)/256

typedef __attribute__((ext_vector_type(4))) float f32x4;
typedef __attribute__((ext_vector_type(8))) int   i32x8;

typedef __attribute__((address_space(3))) uint32_t lds_u32_t;
typedef const __attribute__((address_space(1))) uint32_t gbl_u32_t;

__device__ __forceinline__ void gload_lds16(const void* gsrc, const void* ldst)
{
    __builtin_amdgcn_global_load_lds(
        (gbl_u32_t*)(uintptr_t)gsrc,
        (lds_u32_t*)(uint32_t)(uintptr_t)ldst, 16, 0, 0);
}

__device__ __forceinline__ void blockbar()
{
    asm volatile("" ::: "memory");
    __builtin_amdgcn_s_barrier();
    asm volatile("" ::: "memory");
}

// ---------------------------------------------------------------------------
// Kernel 1: fused prepass (verified rounds 6-11).
// ---------------------------------------------------------------------------
__global__ __launch_bounds__(256) void prep_kernel(
    const float* __restrict__ xs, uint8_t* __restrict__ xq8,
    float* __restrict__ ascale,
    const float* __restrict__ w, uint8_t* __restrict__ wq8)
{
    const int bid = blockIdx.x;
    const int tid = threadIdx.x;
    if (bid < ACT_WGS) {
        const int grp = (bid * 256 + tid) >> 5;
        const int l   = tid & 31;
        const size_t base = (size_t)grp * 128 + (size_t)l * 4;

        const float4 v = *(const float4*)(xs + base);
        float am = fmaxf(fmaxf(fabsf(v.x), fabsf(v.y)),
                         fmaxf(fabsf(v.z), fabsf(v.w)));
#pragma unroll
        for (int off = 1; off <= 16; off <<= 1)
            am = fmaxf(am, __shfl_xor(am, off, 64));

        const float rs = 448.0f / am;
        const float s  = am * (1.0f / 448.0f);

        int pk = __builtin_amdgcn_cvt_pk_fp8_f32(v.x * rs, v.y * rs, 0, false);
        pk     = __builtin_amdgcn_cvt_pk_fp8_f32(v.z * rs, v.w * rs, pk, true);
        *(uint32_t*)(xq8 + base) = (uint32_t)pk;

        if (l == 0) {
            const int kb = grp % KB_;
            const int t  = (grp / KB_) & (T_ - 1);
            const int g  = grp / (KB_ * T_);
            ascale[(((size_t)(g * 4 + (t >> 8))) * KB_ + kb) * 256 + (t & 255)] = s;
        }
    } else {
        const size_t i = ((size_t)(bid - ACT_WGS) * 256 + tid) * 16;
        uint32_t o[4];
#pragma unroll
        for (int q = 0; q < 4; ++q) {
            const float4 a = *(const float4*)(w + i + q * 4);
            int pk = __builtin_amdgcn_cvt_pk_fp8_f32(a.x, a.y, 0, false);
            pk     = __builtin_amdgcn_cvt_pk_fp8_f32(a.z, a.w, pk, true);
            o[q] = (uint32_t)pk;
        }
        *(uint4*)(wq8 + i) = make_uint4(o[0], o[1], o[2], o[3]);
    }
}

// ---------------------------------------------------------------------------
// Kernel 2: producer/consumer blockwise-fp8 grouped GEMM.
//   512 threads, 1 block/CU. Waves 0-3: consumers (64x64 quadrant each,
//   LDS frag reads + mfma_scale 16x16x128 + fp32 rescale; NEVER wait vmcnt).
//   Waves 4-7: producers (all global_load_lds staging into a 3-deep ring,
//   counted vmcnt(8) ledger: tile u+1 guaranteed landed before the barrier
//   that publishes it; tile u+2 stays in flight).
//   Ring: iter u reads buf u%3, fills buf (u+2)%3. One barrier per iter.
//   LDS: A 3x16K @0 | B 3x16K @49152 | ascale 2x4K @98304 | wscale @106496.
// ---------------------------------------------------------------------------
union Frag { i32x8 v; struct { int4 lo, hi; } p; };

#define RD_FRAG(dst, base, r)                                                 \
  { const int rx_ = ((r) & 7) << 4;                                           \
    const char* bp_ = smem + (base) + (r)*128;                                \
    dst.p.lo = *(const int4*)(bp_ + ((lhi*32) ^ rx_));                        \
    dst.p.hi = *(const int4*)(bp_ + ((lhi*32 + 16) ^ rx_)); }

#define STG_A(c, t, bb) gload_lds16(pA8[c] + (size_t)(t)*128,                 \
      smem + (bb)*16384 + (c)*4096 + ptid*16)
#define STG_B(c, t, bb) gload_lds16(pB8[c] + (size_t)(t)*128,                 \
      smem + 49152 + (bb)*16384 + (c)*4096 + ptid*16)
#define STG_S(c) gload_lds16(pS + (size_t)(c)*2048,                           \
      smem + 98304 + ((c)&1)*4096 + ptid*16)

__global__ __launch_bounds__(512, 1) void gemm_fp8_kernel(
    const uint8_t* __restrict__ xq8, const uint8_t* __restrict__ wq8,
    const float* __restrict__ ascale, const float* __restrict__ wscale,
    const float* __restrict__ bias, float* __restrict__ y)
{
    __shared__ char smem[106752];

    const int bx0 = blockIdx.x;
    const int g     = bx0 & 7;          // group == XCD (L2 slab sharing)
    const int inner = bx0 >> 3;         // 0..127
    const int tm    = inner & 7;        // tm fastest: tn-siblings co-resident
    const int tn    = inner >> 3;       // 0..15
    const int t0 = tm * 128, n0 = tn * 128;

    const int tid  = threadIdx.x, lane = tid & 63, wid = tid >> 6;
    const bool producer = (wid >= 4);
    const int ptid = tid & 255;         // producer-local 0..255
    const int l15 = lane & 15, lhi = lane >> 4;
    const int wrow = (wid >> 1) * 64;   // consumer quadrant (wid 0..3)
    const int wcol = (wid & 1) * 64;

    const uint8_t* Ag = xq8 + (size_t)g * T_ * K_;
    const uint8_t* Bg = wq8 + (size_t)g * N_ * K_;

    // producer staging maps: LDS(row = c*32 + ptid/8, slot = ptid&7)
    //   <- global slot ^ (row&7)
    const int srow = ptid >> 3;
    const int xoff = ((ptid & 7) ^ (srow & 7)) * 16;
    const uint8_t* pA8[4];
    const uint8_t* pB8[4];
#pragma unroll
    for (int c = 0; c < 4; ++c) {
        pA8[c] = Ag + (size_t)(t0 + c * 32 + srow) * K_ + xoff;
        pB8[c] = Bg + (size_t)(n0 + c * 32 + srow) * K_ + xoff;
    }
    // ascale chunk source: [8 kb][128 tokens] = 4KB per chunk
    const float* pS = ascale + ((size_t)(g * 4 + (tm >> 1)) * KB_) * 256
                    + (ptid >> 5) * 256 + (tm & 1) * 128 + (ptid & 31) * 4;

    const f32x4 z4 = {0.f, 0.f, 0.f, 0.f};
    f32x4 acc[4][4] = {};
    Frag bF[4];
    f32x4 asv[4];

    // ---- prologue ----
    if (producer) {
        if (ptid < KB_) {
            const float wv = wscale[((size_t)(g * NB_ + tn)) * KB_ + ptid];
            *(float*)(smem + 106496 + ptid * 4) = wv;
        }
        STG_S(0);
#pragma unroll
        for (int c = 0; c < 4; ++c) { STG_A(c, 0, 0); STG_B(c, 0, 0); }
#pragma unroll
        for (int c = 0; c < 4; ++c) { STG_A(c, 1, 1); STG_B(c, 1, 1); }
        asm volatile("s_waitcnt vmcnt(8)" ::: "memory");  // S0 + tile0 landed
    } else {
        __builtin_amdgcn_s_setprio(1);   // consumers keep MFMA priority
    }
    blockbar();

    int cur = 0;
    for (int u = 0; u < NT8_; ++u) {
        const int sbuf = (u >> 3) & 1;

        if (producer) {
            // ---- issue: [ascale chunk]; tile u+2 -> buf (cur+2)%3 ----
            if ((u & 7) == 0 && u + 8 < NT8_) STG_S((u >> 3) + 1);
            if (u + 2 < NT8_) {
                const int fb = (cur + 2 >= 3) ? cur - 1 : cur + 2;
#pragma unroll
                for (int c = 0; c < 4; ++c) { STG_A(c, u + 2, fb); STG_B(c, u + 2, fb); }
                // tile u+1 must be landed; tile u+2 (8 newest) stays in flight
                asm volatile("s_waitcnt vmcnt(8)" ::: "memory");
            } else {
                asm volatile("s_waitcnt vmcnt(0)" ::: "memory");
            }
        } else {
            const float wsc = *(const float*)(smem + 106496 + u * 4);
            const int abase = cur * 16384;
            const int bbase = 49152 + cur * 16384;

            // ---- frag reads (buf cur) + rescale factors ----
#pragma unroll
            for (int n = 0; n < 4; ++n)
                RD_FRAG(bF[n], bbase, wcol + n * 16 + l15);
#pragma unroll
            for (int m = 0; m < 4; ++m) {
                const float4 sv = *(const float4*)(smem + 98304 + sbuf * 4096 +
                    (u & 7) * 512 + (wrow + m * 16 + lhi * 4) * 4);
                asv[m][0] = sv.x * wsc; asv[m][1] = sv.y * wsc;
                asv[m][2] = sv.z * wsc; asv[m][3] = sv.w * wsc;
            }

            // ---- MFMA + rescale ----
#pragma unroll
            for (int m = 0; m < 4; ++m) {
                Frag aF;
                RD_FRAG(aF, abase, wrow + m * 16 + l15);
#pragma unroll
                for (int n = 0; n < 4; ++n) {
                    f32x4 blk = __builtin_amdgcn_mfma_scale_f32_16x16x128_f8f6f4(
                        aF.v, bF[n].v, z4, 0, 0, 0, 0x7F7F7F7F, 0, 0x7F7F7F7F);
                    acc[m][n] += blk * asv[m];
                }
            }
        }

        blockbar();                      // publish tile u+1; free buf cur
        cur = (cur + 1 >= 3) ? 0 : cur + 1;
    }

    // ---- epilogue (consumers): col = lane&15, row = (lane>>4)*4 + j ----
    if (!producer) {
        float* Yg = y + (size_t)g * T_ * N_;
#pragma unroll
        for (int n = 0; n < 4; ++n) {
            const int col = n0 + wcol + n * 16 + l15;
            const float bv = bias[g * N_ + col];
#pragma unroll
            for (int m = 0; m < 4; ++m) {
                const int r0 = t0 + wrow + m * 16 + lhi * 4;
#pragma unroll
                for (int j = 0; j < 4; ++j)
                    Yg[(size_t)(r0 + j) * N_ + col] = acc[m][n][j] + bv;
            }
        }
    }
}

// ---------------------------------------------------------------------------
extern "C" void kernel_launch(void* const* d_in, const int* in_sizes, int n_in,
                              void* d_out, int out_size, void* d_ws, size_t ws_size,
                              hipStream_t stream)
{
    const float* xs     = (const float*)d_in[0];
    const float* weight = (const float*)d_in[1];
    const float* scale  = (const float*)d_in[2];
    const float* bias   = (const float*)d_in[3];
    float* y = (float*)d_out;

    uint8_t* xq8  = (uint8_t*)d_ws;                      //  58,720,256 B
    float*   ascl = (float*)((char*)d_ws + 58720256);    //   1,835,008 B
    uint8_t* wq8  = (uint8_t*)((char*)d_ws + 60555264);  // 117,440,512 B

    prep_kernel<<<ACT_WGS + WREC_WGS, 256, 0, stream>>>(
        xs, xq8, ascl, weight, wq8);

    gemm_fp8_kernel<<<G_ * (T_ / 128) * (N_ / 128), 512, 0, stream>>>(
        xq8, wq8, ascl, scale, bias, y);
}